// Round 11
// baseline (48.802 us; speedup 1.0000x reference)
//
#include <hip/hip_runtime.h>

// GCNAggregator — R11 DIAGNOSTIC (expect dur regression; buys the prep/gather split).
// R8 structure with the prep chain run TWICE (flags keep zero/colcount once):
//   N1 prep_feat(zero=1) ; N2 prep_noise(count=1) ; N1' prep_feat(zero=0) ;
//   N2' prep_noise(count=0) ; G gather.
// prep_chain_warm = R11_total - R8_total(40.0). Model P (prep slow) => ~79;
// Model G1 (first-gather cold) => ~68.

#define B_ 4096
#define K_ 32
#define U_ 16384
#define D_ 256
#define HALF_SLOTS (U_ * D_ / 8)       // 524288 uint4 slots per table

typedef unsigned int uint4n __attribute__((ext_vector_type(4)));

__device__ __forceinline__ unsigned bf16_rne(float x) {
    const unsigned u = __float_as_uint(x);
    return (u + 0x7FFFu + ((u >> 16) & 1u)) >> 16;
}
__device__ __forceinline__ unsigned pack2(float lo, float hi) {
    return bf16_rne(lo) | (bf16_rne(hi) << 16);
}
__device__ __forceinline__ float blo(unsigned v) { return __uint_as_float(v << 16); }
__device__ __forceinline__ float bhi(unsigned v) { return __uint_as_float(v & 0xFFFF0000u); }

__device__ __forceinline__ void conv_slot(const float4* __restrict__ src,
                                          uint4n* __restrict__ packed,
                                          int t, int half_off) {
    const int u = t >> 5;
    const int s = t & 31;
    const float4 a = src[u * (D_ / 4) + s * 2];
    const float4 b = src[u * (D_ / 4) + s * 2 + 1];
    uint4n o;
    o.x = pack2(a.x, a.y);
    o.y = pack2(a.z, a.w);
    o.z = pack2(b.x, b.y);
    o.w = pack2(b.z, b.w);
    __builtin_nontemporal_store(o, &packed[u * 64 + half_off + s]);
}

// N1: (optional) zero colcnt + convert feat half.
__global__ __launch_bounds__(256) void gcn_prep_feat(const float4* __restrict__ feat,
                                                     uint4n* __restrict__ packed,
                                                     int* __restrict__ colcnt,
                                                     int do_zero) {
    const int gid = blockIdx.x * 256 + threadIdx.x;
    if (do_zero && gid < U_) colcnt[gid] = 0;
    conv_slot(feat, packed, gid, 0);
}

// N2: convert noise half + (optional) colcount.
__global__ __launch_bounds__(256) void gcn_prep_noise(const int* __restrict__ idx,
                                                      const float4* __restrict__ noise,
                                                      uint4n* __restrict__ packed,
                                                      int* __restrict__ colcnt,
                                                      int do_count) {
    const int gid = blockIdx.x * 256 + threadIdx.x;
    conv_slot(noise, packed, gid, 32);

    const int wg = gid >> 6;
    if (do_count && wg < B_) {
        const int lane = threadIdx.x & 63;
        const int kk = lane & 31;
        const int u = idx[wg * K_ + kk];
        bool dup = false;
        #pragma unroll
        for (int j = 0; j < K_; ++j) {
            const int uj = __shfl(u, j);
            if (j < kk && uj == u) dup = true;
        }
        if (lane < 32 && !dup) atomicAdd(&colcnt[u], 1);
    }
}

// G: gather. One wave per row; lanes 0..31 feat dims, 32..63 noise dims.
__global__ __launch_bounds__(256) void gcn_gather(const int* __restrict__ idx,
                                                  const uint4n* __restrict__ packed,
                                                  const int* __restrict__ colcnt,
                                                  float4* __restrict__ out) {
    const int row = blockIdx.x * 4 + (threadIdx.x >> 6);
    const int lane = threadIdx.x & 63;

    const int kk = lane & 31;
    const int u = idx[row * K_ + kk];

    bool dup = false;
    #pragma unroll
    for (int j = 0; j < K_; ++j) {
        const int uj = __shfl(u, j);
        if (j < kk && uj == u) dup = true;
    }
    const int rowcnt = __popcll(__ballot(!dup) & 0xFFFFFFFFull);

    float w = 0.0f;
    if (!dup) w = rsqrtf((float)(rowcnt * colcnt[u]));

    int us[K_]; float wk[K_];
    #pragma unroll
    for (int k = 0; k < K_; ++k) {
        us[k] = __builtin_amdgcn_readlane(u, k);
        wk[k] = __uint_as_float(
            (unsigned)__builtin_amdgcn_readlane((int)__float_as_uint(w), k));
    }

    float a0 = 0.f, a1 = 0.f, a2 = 0.f, a3 = 0.f;
    float a4 = 0.f, a5 = 0.f, a6 = 0.f, a7 = 0.f;

    #pragma unroll
    for (int k = 0; k < K_; ++k) {
        const uint4n v = packed[us[k] * 64 + lane];
        const float wkk = wk[k];
        a0 = fmaf(wkk, blo(v.x), a0);
        a1 = fmaf(wkk, bhi(v.x), a1);
        a2 = fmaf(wkk, blo(v.y), a2);
        a3 = fmaf(wkk, bhi(v.y), a3);
        a4 = fmaf(wkk, blo(v.z), a4);
        a5 = fmaf(wkk, bhi(v.z), a5);
        a6 = fmaf(wkk, blo(v.w), a6);
        a7 = fmaf(wkk, bhi(v.w), a7);
    }

    const int base = (lane < 32)
        ? (row * (D_ / 4) + lane * 2)
        : (B_ * (D_ / 4) + row * (D_ / 4) + (lane - 32) * 2);
    out[base]     = make_float4(a0, a1, a2, a3);
    out[base + 1] = make_float4(a4, a5, a6, a7);
}

extern "C" void kernel_launch(void* const* d_in, const int* in_sizes, int n_in,
                              void* d_out, int out_size, void* d_ws, size_t ws_size,
                              hipStream_t stream) {
    const int*    idx   = (const int*)d_in[0];        // [B,K] int32
    const float4* feat  = (const float4*)d_in[1];     // [U,D] f32
    const float4* noise = (const float4*)d_in[2];     // [U,D] f32
    float4*       out   = (float4*)d_out;             // [2*B, D] f32

    uint4n* packed = (uint4n*)d_ws;                   // 16 MiB packed bf16 table
    int*    colcnt = (int*)((char*)d_ws + 32u * 1024 * 1024);  // 64 KiB

    // prep chain #1 (real)
    gcn_prep_feat <<<HALF_SLOTS / 256, 256, 0, stream>>>(feat, packed, colcnt, 1);
    gcn_prep_noise<<<HALF_SLOTS / 256, 256, 0, stream>>>(idx, noise, packed, colcnt, 1);
    // prep chain #2 (DIAGNOSTIC duplicate; idempotent, no re-zero / re-count)
    gcn_prep_feat <<<HALF_SLOTS / 256, 256, 0, stream>>>(feat, packed, colcnt, 0);
    gcn_prep_noise<<<HALF_SLOTS / 256, 256, 0, stream>>>(idx, noise, packed, colcnt, 0);

    gcn_gather    <<<B_ / 4,          256, 0, stream>>>(idx, packed, colcnt, out);
}